// Round 2
// baseline (288.667 us; speedup 1.0000x reference)
//
#include <hip/hip_runtime.h>
#include <hip/hip_bf16.h>

// B=32, S=2048, H=512, fp32 in/out.
// scores = tanh(Y@W + b).w -> softmax(S) -> c_star = alpha@Y
// GEMM: 128x128 tile, BK=32, DOUBLE-BUFFERED LDS (2-phase pipeline):
// per K-step, issue global_load_lds for tile t+1 into buf^1, then
// ds_read+cvt+MFMA tile t from buf, then ONE __syncthreads (its vmcnt(0)
// drain pays only the residual latency left after the compute phase).
// A staged as RAW fp32 via llds, converted fp32->fp16 RNE after ds_read,
// in registers. Both LDS tiles chunk-XOR swizzled via gptr permutation.
// Tail: softmax (sums 4 col-partials) + two-stage contiguous wsum.

#define Bsz 32
#define Ssz 2048
#define Hsz 512
#define Msz (Bsz * Ssz)   // 65536

using half8   = __attribute__((ext_vector_type(8))) _Float16;
using floatx4 = __attribute__((ext_vector_type(4))) float;

__device__ __forceinline__ void llds16(void* l, const void* g) {
  __builtin_amdgcn_global_load_lds((const __attribute__((address_space(1))) void*)g,
                                   (__attribute__((address_space(3))) void*)l, 16, 0, 0);
}

__device__ __forceinline__ float fast_tanh(float x) {
  const float e = __expf(2.f * x);
  return 1.f - 2.f / (e + 1.f);
}

// ---- W[k][n] fp32 -> Wt[n][k] fp16 (transpose + RNE cast) ----
__global__ __launch_bounds__(256) void wsplit_k(const float* __restrict__ W,
                                                _Float16* __restrict__ Wt) {
  __shared__ float tile[32][33];
  const int bx = blockIdx.x & 15, by = blockIdx.x >> 4;
  const int tx = threadIdx.x & 31, ty = threadIdx.x >> 5;
#pragma unroll
  for (int i = 0; i < 4; ++i)
    tile[ty + 8 * i][tx] = W[(size_t)(by * 32 + ty + 8 * i) * Hsz + bx * 32 + tx];
  __syncthreads();
#pragma unroll
  for (int i = 0; i < 4; ++i) {
    const int n = bx * 32 + ty + 8 * i;
    const int k = by * 32 + tx;
    Wt[(size_t)n * Hsz + k] = (_Float16)tile[tx][ty + 8 * i];
  }
}

// ---- GEMM + tanh.w partial-score epilogue ----
__global__ __launch_bounds__(256) void gemm_score_k(const float* __restrict__ Y,
                                                    const _Float16* __restrict__ Wt,
                                                    const float* __restrict__ bvec,
                                                    const float* __restrict__ wvec,
                                                    float* __restrict__ scores4) {
  __shared__ __align__(16) float    As[2 * 128 * 32];   // 2 x 16 KB fp32, chunk-swizzled
  __shared__ __align__(16) _Float16 Bs[2 * 128 * 32];   // 2 x  8 KB fp16, chunk-swizzled
  const int tid = threadIdx.x;
  const int lane = tid & 63, wv = tid >> 6;
  const int wr = wv >> 1, wc = wv & 1;
  const int lr = lane & 15, lq = lane >> 4;
  // XCD-aware decode: 4 nblk-siblings of one mblk share (g&7) -> same XCD L2.
  const int g = blockIdx.x;
  const int x = g & 7, q = g >> 3;
  const int nblk = q & 3;
  const int mblk = (q >> 2) * 8 + x;

  floatx4 acc[4][4];
#pragma unroll
  for (int rf = 0; rf < 4; ++rf)
#pragma unroll
    for (int cf = 0; cf < 4; ++cf)
      acc[rf][cf] = (floatx4){0.f, 0.f, 0.f, 0.f};

  const float* aY = Y + (size_t)mblk * 128 * Hsz;
  const _Float16* bW = Wt + (size_t)nblk * 128 * Hsz;

  // Stage K-tile 'it_' into LDS buffer 'buf'.
  // A: 1024 chunks of 16B (row=chunk>>3), gptr permuted within the row's
  // 128B window: at LDS slot s we store global chunk s^(row&7).
  // B: 512 chunks (row=chunk>>2), permuted within the row's 64B window.
  auto stage = [&](int buf, int it_) {
    const int k0 = it_ * 32;
#pragma unroll
    for (int i = 0; i < 4; ++i) {
      const int cb = i * 256 + wv * 64;        // wave-uniform chunk base
      const int p = cb + lane;
      const int row = p >> 3;
      const int gc = (p & 7) ^ (row & 7);
      llds16(&As[buf * 4096 + cb * 4], aY + (size_t)row * Hsz + k0 + gc * 4);
    }
#pragma unroll
    for (int i = 0; i < 2; ++i) {
      const int cb = i * 256 + wv * 64;
      const int p = cb + lane;
      const int row = p >> 2;
      const int gc = (p & 3) ^ ((row >> 1) & 3);
      llds16(&Bs[buf * 4096 + cb * 8], bW + (size_t)row * Hsz + k0 + gc * 8);
    }
  };

  // Prologue: stage tile 0, drain, then 2-phase pipeline with ONE barrier/iter.
  stage(0, 0);
  __syncthreads();

  for (int it = 0; it < 16; ++it) {
    const int cur = it & 1;
    if (it < 15) stage(cur ^ 1, it + 1);   // prefetch next tile (latency hides under compute)

    const float*    Asb = As + cur * 4096;
    const _Float16* Bsb = Bs + cur * 4096;

    half8 a[4], bf[4];
#pragma unroll
    for (int rf = 0; rf < 4; ++rf) {
      const int ar = wr * 64 + rf * 16 + lr;
      const int s0 = (lq * 2) ^ (ar & 7);      // slot of k-chunk lq*2
      const float4 flo = *(const float4*)&Asb[ar * 32 + s0 * 4];
      const float4 fhi = *(const float4*)&Asb[ar * 32 + (s0 ^ 1) * 4];
      half8 h;
      h[0] = (_Float16)flo.x; h[1] = (_Float16)flo.y;
      h[2] = (_Float16)flo.z; h[3] = (_Float16)flo.w;
      h[4] = (_Float16)fhi.x; h[5] = (_Float16)fhi.y;
      h[6] = (_Float16)fhi.z; h[7] = (_Float16)fhi.w;
      a[rf] = h;
    }
#pragma unroll
    for (int cf = 0; cf < 4; ++cf) {
      const int nr = wc * 64 + cf * 16 + lr;
      bf[cf] = *(const half8*)&Bsb[nr * 32 + (lq ^ ((nr >> 1) & 3)) * 8];
    }
#pragma unroll
    for (int rf = 0; rf < 4; ++rf)
#pragma unroll
      for (int cf = 0; cf < 4; ++cf)
        acc[rf][cf] = __builtin_amdgcn_mfma_f32_16x16x32_f16(a[rf], bf[cf], acc[rf][cf], 0, 0, 0);

    __syncthreads();   // drains prefetch vmcnt (residual only) + protects buf swap
  }

  // Epilogue: v = sum_cols tanh(pre+b)*w; 16-lane shuffle reduce;
  // combine 2 col-waves via LDS; non-atomic per-nblk partial store.
  float bb[4], ww[4];
  const int colbase = nblk * 128 + wc * 64;
#pragma unroll
  for (int cf = 0; cf < 4; ++cf) {
    const int col = colbase + cf * 16 + lr;
    bb[cf] = bvec[col];
    ww[cf] = wvec[col];
  }
  float* red = (float*)As;  // 256 floats, reuse LDS
#pragma unroll
  for (int rf = 0; rf < 4; ++rf) {
#pragma unroll
    for (int r = 0; r < 4; ++r) {
      float v = 0.f;
#pragma unroll
      for (int cf = 0; cf < 4; ++cf)
        v += fast_tanh(acc[rf][cf][r] + bb[cf]) * ww[cf];
      v += __shfl_xor(v, 1, 16);
      v += __shfl_xor(v, 2, 16);
      v += __shfl_xor(v, 4, 16);
      v += __shfl_xor(v, 8, 16);
      if (lr == 0)
        red[(wr * 64 + rf * 16 + lq * 4 + r) * 2 + wc] = v;
    }
  }
  __syncthreads();
  if (tid < 128)
    scores4[(size_t)nblk * Msz + mblk * 128 + tid] = red[2 * tid] + red[2 * tid + 1];
}

// ---- softmax over S, summing 4 nblk partials -> alpha ----
__global__ __launch_bounds__(256) void softmax_k(const float* __restrict__ scores4,
                                                 const float* __restrict__ mask,
                                                 float* __restrict__ alpha) {
  const int b = blockIdx.x, t = threadIdx.x;
  const int lane = t & 63, wv = t >> 6;
  float s[8];
  float mx = -3.4e38f;
#pragma unroll
  for (int i = 0; i < 8; ++i) {
    const int idx = b * Ssz + i * 256 + t;
    float v = scores4[idx] + scores4[Msz + idx] + scores4[2 * Msz + idx] + scores4[3 * Msz + idx];
    v -= 1000.f * (1.f - mask[idx]);
    s[i] = v;
    mx = fmaxf(mx, v);
  }
  for (int off = 32; off > 0; off >>= 1) mx = fmaxf(mx, __shfl_xor(mx, off, 64));
  __shared__ float rm[4], rs[4];
  if (lane == 0) rm[wv] = mx;
  __syncthreads();
  mx = fmaxf(fmaxf(rm[0], rm[1]), fmaxf(rm[2], rm[3]));
  float sum = 0.f;
#pragma unroll
  for (int i = 0; i < 8; ++i) {
    s[i] = __expf(s[i] - mx);
    sum += s[i];
  }
  for (int off = 32; off > 0; off >>= 1) sum += __shfl_xor(sum, off, 64);
  if (lane == 0) rs[wv] = sum;
  __syncthreads();
  sum = rs[0] + rs[1] + rs[2] + rs[3];
  const float inv = 1.f / sum;
#pragma unroll
  for (int i = 0; i < 8; ++i) alpha[b * Ssz + i * 256 + t] = s[i] * inv;
}

// ---- stage 1: partial sums of alpha*Y over 64-row slabs (contiguous 128KB) ----
__global__ __launch_bounds__(256) void wsum1_k(const float* __restrict__ alpha,
                                               const float* __restrict__ Y,
                                               float* __restrict__ partial) {
  const int b = blockIdx.x >> 5, sc = blockIdx.x & 31;
  const int t = threadIdx.x, lane = t & 63, wv = t >> 6;
  __shared__ float part[4 * 512];
  const int s0 = sc * 64 + wv * 16;
  const float* al = alpha + b * Ssz + s0;
  const float4* Yb = (const float4*)(Y + ((size_t)b * Ssz + s0) * Hsz);
  float a0 = 0.f, a1 = 0.f, a2 = 0.f, a3 = 0.f, a4 = 0.f, a5 = 0.f, a6 = 0.f, a7 = 0.f;
#pragma unroll 4
  for (int r = 0; r < 16; ++r) {
    const float a = al[r];
    const float4 y0 = Yb[r * 128 + lane * 2];
    const float4 y1 = Yb[r * 128 + lane * 2 + 1];
    a0 = fmaf(a, y0.x, a0); a1 = fmaf(a, y0.y, a1);
    a2 = fmaf(a, y0.z, a2); a3 = fmaf(a, y0.w, a3);
    a4 = fmaf(a, y1.x, a4); a5 = fmaf(a, y1.y, a5);
    a6 = fmaf(a, y1.z, a6); a7 = fmaf(a, y1.w, a7);
  }
  part[wv * 512 + 0 * 64 + lane] = a0;
  part[wv * 512 + 1 * 64 + lane] = a1;
  part[wv * 512 + 2 * 64 + lane] = a2;
  part[wv * 512 + 3 * 64 + lane] = a3;
  part[wv * 512 + 4 * 64 + lane] = a4;
  part[wv * 512 + 5 * 64 + lane] = a5;
  part[wv * 512 + 6 * 64 + lane] = a6;
  part[wv * 512 + 7 * 64 + lane] = a7;
  __syncthreads();
#pragma unroll
  for (int i = 0; i < 2; ++i) {
    const int h = i * 256 + t;
    const int idx = (h & 7) * 64 + (h >> 3);
    partial[((size_t)(b * 32 + sc)) * Hsz + h] =
        part[idx] + part[512 + idx] + part[1024 + idx] + part[1536 + idx];
  }
}

// ---- stage 2: out[b][h] = sum over 32 sc of partial ----
__global__ __launch_bounds__(256) void wsum2_k(const float* __restrict__ partial,
                                               float* __restrict__ out) {
  const int b = blockIdx.x >> 1;
  const int h = (blockIdx.x & 1) * 256 + threadIdx.x;
  float s = 0.f;
#pragma unroll 8
  for (int sc = 0; sc < 32; ++sc)
    s += partial[((size_t)(b * 32 + sc)) * Hsz + h];
  out[b * Hsz + h] = s;
}

extern "C" void kernel_launch(void* const* d_in, const int* in_sizes, int n_in,
                              void* d_out, int out_size, void* d_ws, size_t ws_size,
                              hipStream_t stream) {
  (void)in_sizes; (void)n_in; (void)out_size; (void)ws_size;
  const float* Y    = (const float*)d_in[0];
  const float* mask = (const float*)d_in[1];
  const float* W    = (const float*)d_in[2];
  const float* bvec = (const float*)d_in[3];
  const float* wvec = (const float*)d_in[4];
  float* out = (float*)d_out;

  char* ws = (char*)d_ws;
  _Float16* Wt   = (_Float16*)ws;                            // 512 KB
  float* scores4 = (float*)(ws + ((size_t)1 << 20));         // 1 MB (4 partials)
  float* alpha   = (float*)(ws + ((size_t)2 << 20));         // 256 KB
  float* partial = (float*)(ws + ((size_t)3 << 20));         // 2 MB

  wsplit_k<<<256, 256, 0, stream>>>(W, Wt);
  gemm_score_k<<<(Msz / 128) * 4, 256, 0, stream>>>(Y, Wt, bvec, wvec, scores4);
  softmax_k<<<Bsz, 256, 0, stream>>>(scores4, mask, alpha);
  wsum1_k<<<Bsz * 32, 256, 0, stream>>>(alpha, Y, partial);
  wsum2_k<<<Bsz * 2, 256, 0, stream>>>(partial, out);
}

// Round 3
// 284.819 us; speedup vs baseline: 1.0135x; 1.0135x over previous
//
#include <hip/hip_runtime.h>
#include <hip/hip_bf16.h>

// B=32, S=2048, H=512, fp32 in/out.
// scores = tanh(Y@W + b).w -> softmax(S) -> c_star = alpha@Y
// GEMM: 128x128 tile, BK=32, double-buffered LDS with COUNTED-vmcnt
// pipeline (T4): prologue stages K-tiles 0,1; iter t waits vmcnt(6)
// (stage t landed, stage t+1 still in flight), raw s_barrier, frag
// ds_reads, lgkmcnt(0)+s_barrier (reads done -> safe overwrite), then
// issues stage t+2 into the just-read buffer, then 16 MFMA. vmcnt never
// drains to 0 in the main loop (AITER pattern) -> global_load_lds
// latency spans 2 full iterations.
// A staged RAW fp32 via llds, cvt fp32->fp16 RNE after ds_read.
// Both LDS tiles chunk-XOR swizzled via gptr permutation.
// Tail: softmax (sums 4 col-partials) + two-stage contiguous wsum.

#define Bsz 32
#define Ssz 2048
#define Hsz 512
#define Msz (Bsz * Ssz)   // 65536

using half8   = __attribute__((ext_vector_type(8))) _Float16;
using floatx4 = __attribute__((ext_vector_type(4))) float;

__device__ __forceinline__ void llds16(void* l, const void* g) {
  __builtin_amdgcn_global_load_lds((const __attribute__((address_space(1))) void*)g,
                                   (__attribute__((address_space(3))) void*)l, 16, 0, 0);
}

__device__ __forceinline__ float fast_tanh(float x) {
  const float e = __expf(2.f * x);
  return 1.f - 2.f / (e + 1.f);
}

// ---- W[k][n] fp32 -> Wt[n][k] fp16 (transpose + RNE cast) ----
__global__ __launch_bounds__(256) void wsplit_k(const float* __restrict__ W,
                                                _Float16* __restrict__ Wt) {
  __shared__ float tile[32][33];
  const int bx = blockIdx.x & 15, by = blockIdx.x >> 4;
  const int tx = threadIdx.x & 31, ty = threadIdx.x >> 5;
#pragma unroll
  for (int i = 0; i < 4; ++i)
    tile[ty + 8 * i][tx] = W[(size_t)(by * 32 + ty + 8 * i) * Hsz + bx * 32 + tx];
  __syncthreads();
#pragma unroll
  for (int i = 0; i < 4; ++i) {
    const int n = bx * 32 + ty + 8 * i;
    const int k = by * 32 + tx;
    Wt[(size_t)n * Hsz + k] = (_Float16)tile[tx][ty + 8 * i];
  }
}

// ---- GEMM + tanh.w partial-score epilogue ----
__global__ __launch_bounds__(256) void gemm_score_k(const float* __restrict__ Y,
                                                    const _Float16* __restrict__ Wt,
                                                    const float* __restrict__ bvec,
                                                    const float* __restrict__ wvec,
                                                    float* __restrict__ scores4) {
  __shared__ __align__(16) float    As[2 * 128 * 32];   // 2 x 16 KB fp32, chunk-swizzled
  __shared__ __align__(16) _Float16 Bs[2 * 128 * 32];   // 2 x  8 KB fp16, chunk-swizzled
  const int tid = threadIdx.x;
  const int lane = tid & 63, wv = tid >> 6;
  const int wr = wv >> 1, wc = wv & 1;
  const int lr = lane & 15, lq = lane >> 4;
  // XCD-aware decode: 4 nblk-siblings of one mblk share (g&7) -> same XCD L2.
  const int g = blockIdx.x;
  const int x = g & 7, q = g >> 3;
  const int nblk = q & 3;
  const int mblk = (q >> 2) * 8 + x;

  floatx4 acc[4][4];
#pragma unroll
  for (int rf = 0; rf < 4; ++rf)
#pragma unroll
    for (int cf = 0; cf < 4; ++cf)
      acc[rf][cf] = (floatx4){0.f, 0.f, 0.f, 0.f};

  const float* aY = Y + (size_t)mblk * 128 * Hsz;
  const _Float16* bW = Wt + (size_t)nblk * 128 * Hsz;

  // Per-thread staging descriptors (running global pointers, advance one
  // K-tile per stage call; LDS chunk bases are buf-relative).
  // A: 1024 chunks of 16B (row=chunk>>3), gptr permuted within the row's
  // 128B window: at LDS slot s we store global chunk s^(row&7).
  // B: 512 chunks (row=chunk>>2), permuted within the row's 64B window.
  int aLds[4]; const float* aG[4];
#pragma unroll
  for (int i = 0; i < 4; ++i) {
    const int cb = i * 256 + wv * 64;        // wave-uniform chunk base
    const int p = cb + lane;
    const int row = p >> 3;
    const int gc = (p & 7) ^ (row & 7);
    aLds[i] = cb * 4;
    aG[i] = aY + (size_t)row * Hsz + gc * 4;
  }
  int bLds[2]; const _Float16* bG[2];
#pragma unroll
  for (int i = 0; i < 2; ++i) {
    const int cb = i * 256 + wv * 64;
    const int p = cb + lane;
    const int row = p >> 2;
    const int gc = (p & 3) ^ ((row >> 1) & 3);
    bLds[i] = cb * 8;
    bG[i] = bW + (size_t)row * Hsz + gc * 8;
  }

  auto stage = [&](int bufOff) {   // bufOff in elements: 0 or 4096 (both arrays)
#pragma unroll
    for (int i = 0; i < 4; ++i) { llds16(&As[bufOff + aLds[i]], aG[i]); aG[i] += 32; }
#pragma unroll
    for (int i = 0; i < 2; ++i) { llds16(&Bs[bufOff + bLds[i]], bG[i]); bG[i] += 32; }
  };

  // Prologue: 2-deep prefetch. S0 -> buf0, S1 -> buf1 (12 llds outstanding).
  stage(0);
  stage(4096);

  for (int it = 0; it < 16; ++it) {
    // Counted wait: retire stage(it) (oldest 6); stage(it+1) stays in flight.
    if (it < 15) { asm volatile("s_waitcnt vmcnt(6)" ::: "memory"); }
    else         { asm volatile("s_waitcnt vmcnt(0)" ::: "memory"); }
    __builtin_amdgcn_sched_barrier(0);
    __builtin_amdgcn_s_barrier();          // buf[it&1] ready for all waves

    const int bufOff = (it & 1) * 4096;
    const float*    Asb = As + bufOff;
    const _Float16* Bsb = Bs + bufOff;

    half8 a[4], bf[4];
#pragma unroll
    for (int rf = 0; rf < 4; ++rf) {
      const int ar = wr * 64 + rf * 16 + lr;
      const int s0 = (lq * 2) ^ (ar & 7);      // slot of k-chunk lq*2
      const float4 flo = *(const float4*)&Asb[ar * 32 + s0 * 4];
      const float4 fhi = *(const float4*)&Asb[ar * 32 + (s0 ^ 1) * 4];
      half8 h;
      h[0] = (_Float16)flo.x; h[1] = (_Float16)flo.y;
      h[2] = (_Float16)flo.z; h[3] = (_Float16)flo.w;
      h[4] = (_Float16)fhi.x; h[5] = (_Float16)fhi.y;
      h[6] = (_Float16)fhi.z; h[7] = (_Float16)fhi.w;
      a[rf] = h;
    }
#pragma unroll
    for (int cf = 0; cf < 4; ++cf) {
      const int nr = wc * 64 + cf * 16 + lr;
      bf[cf] = *(const half8*)&Bsb[nr * 32 + (lq ^ ((nr >> 1) & 3)) * 8];
    }

    // My frag reads are complete -> after the barrier, EVERY wave's reads of
    // buf[it&1] are complete -> safe to overwrite it with stage(it+2).
    asm volatile("s_waitcnt lgkmcnt(0)" ::: "memory");
    __builtin_amdgcn_sched_barrier(0);
    __builtin_amdgcn_s_barrier();
    __builtin_amdgcn_sched_barrier(0);
    if (it < 14) stage(bufOff);            // S_{it+2} -> same-parity buffer

#pragma unroll
    for (int rf = 0; rf < 4; ++rf)
#pragma unroll
      for (int cf = 0; cf < 4; ++cf)
        acc[rf][cf] = __builtin_amdgcn_mfma_f32_16x16x32_f16(a[rf], bf[cf], acc[rf][cf], 0, 0, 0);
  }

  // Epilogue: v = sum_cols tanh(pre+b)*w; 16-lane shuffle reduce;
  // combine 2 col-waves via LDS; non-atomic per-nblk partial store.
  // (Loop's final barrier guarantees all ds_reads of As are retired, and no
  // llds is outstanding, before red overwrites As.)
  float bb[4], ww[4];
  const int colbase = nblk * 128 + wc * 64;
#pragma unroll
  for (int cf = 0; cf < 4; ++cf) {
    const int col = colbase + cf * 16 + lr;
    bb[cf] = bvec[col];
    ww[cf] = wvec[col];
  }
  float* red = (float*)As;  // 256 floats, reuse LDS
#pragma unroll
  for (int rf = 0; rf < 4; ++rf) {
#pragma unroll
    for (int r = 0; r < 4; ++r) {
      float v = 0.f;
#pragma unroll
      for (int cf = 0; cf < 4; ++cf)
        v += fast_tanh(acc[rf][cf][r] + bb[cf]) * ww[cf];
      v += __shfl_xor(v, 1, 16);
      v += __shfl_xor(v, 2, 16);
      v += __shfl_xor(v, 4, 16);
      v += __shfl_xor(v, 8, 16);
      if (lr == 0)
        red[(wr * 64 + rf * 16 + lq * 4 + r) * 2 + wc] = v;
    }
  }
  __syncthreads();
  if (tid < 128)
    scores4[(size_t)nblk * Msz + mblk * 128 + tid] = red[2 * tid] + red[2 * tid + 1];
}

// ---- softmax over S, summing 4 nblk partials -> alpha ----
__global__ __launch_bounds__(256) void softmax_k(const float* __restrict__ scores4,
                                                 const float* __restrict__ mask,
                                                 float* __restrict__ alpha) {
  const int b = blockIdx.x, t = threadIdx.x;
  const int lane = t & 63, wv = t >> 6;
  float s[8];
  float mx = -3.4e38f;
#pragma unroll
  for (int i = 0; i < 8; ++i) {
    const int idx = b * Ssz + i * 256 + t;
    float v = scores4[idx] + scores4[Msz + idx] + scores4[2 * Msz + idx] + scores4[3 * Msz + idx];
    v -= 1000.f * (1.f - mask[idx]);
    s[i] = v;
    mx = fmaxf(mx, v);
  }
  for (int off = 32; off > 0; off >>= 1) mx = fmaxf(mx, __shfl_xor(mx, off, 64));
  __shared__ float rm[4], rs[4];
  if (lane == 0) rm[wv] = mx;
  __syncthreads();
  mx = fmaxf(fmaxf(rm[0], rm[1]), fmaxf(rm[2], rm[3]));
  float sum = 0.f;
#pragma unroll
  for (int i = 0; i < 8; ++i) {
    s[i] = __expf(s[i] - mx);
    sum += s[i];
  }
  for (int off = 32; off > 0; off >>= 1) sum += __shfl_xor(sum, off, 64);
  if (lane == 0) rs[wv] = sum;
  __syncthreads();
  sum = rs[0] + rs[1] + rs[2] + rs[3];
  const float inv = 1.f / sum;
#pragma unroll
  for (int i = 0; i < 8; ++i) alpha[b * Ssz + i * 256 + t] = s[i] * inv;
}

// ---- stage 1: partial sums of alpha*Y over 64-row slabs (contiguous 128KB) ----
__global__ __launch_bounds__(256) void wsum1_k(const float* __restrict__ alpha,
                                               const float* __restrict__ Y,
                                               float* __restrict__ partial) {
  const int b = blockIdx.x >> 5, sc = blockIdx.x & 31;
  const int t = threadIdx.x, lane = t & 63, wv = t >> 6;
  __shared__ float part[4 * 512];
  const int s0 = sc * 64 + wv * 16;
  const float* al = alpha + b * Ssz + s0;
  const float4* Yb = (const float4*)(Y + ((size_t)b * Ssz + s0) * Hsz);
  float a0 = 0.f, a1 = 0.f, a2 = 0.f, a3 = 0.f, a4 = 0.f, a5 = 0.f, a6 = 0.f, a7 = 0.f;
#pragma unroll 4
  for (int r = 0; r < 16; ++r) {
    const float a = al[r];
    const float4 y0 = Yb[r * 128 + lane * 2];
    const float4 y1 = Yb[r * 128 + lane * 2 + 1];
    a0 = fmaf(a, y0.x, a0); a1 = fmaf(a, y0.y, a1);
    a2 = fmaf(a, y0.z, a2); a3 = fmaf(a, y0.w, a3);
    a4 = fmaf(a, y1.x, a4); a5 = fmaf(a, y1.y, a5);
    a6 = fmaf(a, y1.z, a6); a7 = fmaf(a, y1.w, a7);
  }
  part[wv * 512 + 0 * 64 + lane] = a0;
  part[wv * 512 + 1 * 64 + lane] = a1;
  part[wv * 512 + 2 * 64 + lane] = a2;
  part[wv * 512 + 3 * 64 + lane] = a3;
  part[wv * 512 + 4 * 64 + lane] = a4;
  part[wv * 512 + 5 * 64 + lane] = a5;
  part[wv * 512 + 6 * 64 + lane] = a6;
  part[wv * 512 + 7 * 64 + lane] = a7;
  __syncthreads();
#pragma unroll
  for (int i = 0; i < 2; ++i) {
    const int h = i * 256 + t;
    const int idx = (h & 7) * 64 + (h >> 3);
    partial[((size_t)(b * 32 + sc)) * Hsz + h] =
        part[idx] + part[512 + idx] + part[1024 + idx] + part[1536 + idx];
  }
}

// ---- stage 2: out[b][h] = sum over 32 sc of partial ----
__global__ __launch_bounds__(256) void wsum2_k(const float* __restrict__ partial,
                                               float* __restrict__ out) {
  const int b = blockIdx.x >> 1;
  const int h = (blockIdx.x & 1) * 256 + threadIdx.x;
  float s = 0.f;
#pragma unroll 8
  for (int sc = 0; sc < 32; ++sc)
    s += partial[((size_t)(b * 32 + sc)) * Hsz + h];
  out[b * Hsz + h] = s;
}

extern "C" void kernel_launch(void* const* d_in, const int* in_sizes, int n_in,
                              void* d_out, int out_size, void* d_ws, size_t ws_size,
                              hipStream_t stream) {
  (void)in_sizes; (void)n_in; (void)out_size; (void)ws_size;
  const float* Y    = (const float*)d_in[0];
  const float* mask = (const float*)d_in[1];
  const float* W    = (const float*)d_in[2];
  const float* bvec = (const float*)d_in[3];
  const float* wvec = (const float*)d_in[4];
  float* out = (float*)d_out;

  char* ws = (char*)d_ws;
  _Float16* Wt   = (_Float16*)ws;                            // 512 KB
  float* scores4 = (float*)(ws + ((size_t)1 << 20));         // 1 MB (4 partials)
  float* alpha   = (float*)(ws + ((size_t)2 << 20));         // 256 KB
  float* partial = (float*)(ws + ((size_t)3 << 20));         // 2 MB

  wsplit_k<<<256, 256, 0, stream>>>(W, Wt);
  gemm_score_k<<<(Msz / 128) * 4, 256, 0, stream>>>(Y, Wt, bvec, wvec, scores4);
  softmax_k<<<Bsz, 256, 0, stream>>>(scores4, mask, alpha);
  wsum1_k<<<Bsz * 32, 256, 0, stream>>>(alpha, Y, partial);
  wsum2_k<<<Bsz * 2, 256, 0, stream>>>(partial, out);
}